// Round 4
// baseline (333.252 us; speedup 1.0000x reference)
//
#include <hip/hip_runtime.h>
#include <math.h>

// SeesawLoss, one-hot specialization:
//   loss[n] = log(denom[n] + eps) - (l[n,i] - m[n]),  i = label of row n
//   denom[n] = sum_j s[i,j]*e[n,j] - s[i,i]*e[n,i] + e[n,i],  e = exp(l - m)
// Memory-bound: reads logits (161MB) + targets (161MB) + s (6MB, L2/L3-cached).
// Roofline: ~330MB / 6.3 TB/s ≈ 52 us.

constexpr int N_ROWS = 32768;
constexpr int C_CLS  = 1230;
constexpr int C2     = C_CLS / 2;              // 615 float2 per row (4920B rows, 8B-aligned)
constexpr int BLK    = 256;
constexpr int PER_T  = (C2 + BLK - 1) / BLK;   // 3
constexpr float EPS_F = 1e-6f;

__global__ __launch_bounds__(BLK) void seesaw_row_kernel(
    const float* __restrict__ logits,
    const float* __restrict__ targets,
    const float* __restrict__ s,
    float* __restrict__ row_loss)
{
    const int n    = blockIdx.x;
    const int t    = threadIdx.x;
    const int lane = t & 63;
    const int wv   = t >> 6;

    const float2* lrow = reinterpret_cast<const float2*>(logits  + (size_t)n * C_CLS);
    const float2* trow = reinterpret_cast<const float2*>(targets + (size_t)n * C_CLS);

    __shared__ float red_max[4];
    __shared__ float red_sum[4];
    __shared__ int   sh_label;   // exactly one writer (one-hot targets)
    __shared__ float sh_lval;    // logit at the label column

    // ---- Phase A: load row, find max + label -------------------------------
    float2 l[PER_T];
    float lmax = -INFINITY;
    #pragma unroll
    for (int k = 0; k < PER_T; ++k) {
        const int j2 = t + k * BLK;
        if (j2 < C2) {
            l[k] = lrow[j2];
            const float2 tv = trow[j2];
            lmax = fmaxf(lmax, fmaxf(l[k].x, l[k].y));
            if (tv.x > 0.5f) { sh_label = 2 * j2;     sh_lval = l[k].x; }
            if (tv.y > 0.5f) { sh_label = 2 * j2 + 1; sh_lval = l[k].y; }
        }
    }
    // wave64 max reduce, then across the 4 waves via LDS
    #pragma unroll
    for (int off = 32; off > 0; off >>= 1)
        lmax = fmaxf(lmax, __shfl_down(lmax, off));
    if (lane == 0) red_max[wv] = lmax;
    __syncthreads();
    const float m  = fmaxf(fmaxf(red_max[0], red_max[1]),
                           fmaxf(red_max[2], red_max[3]));
    const int   li = sh_label;
    const float lv = sh_lval;

    // ---- Phase B: e = exp(l - m); dot with gathered s[li,:] ----------------
    const float2* srow = reinterpret_cast<const float2*>(s + (size_t)li * C_CLS);
    // hoist the diagonal load so it overlaps the dot loop
    const float sii = s[(size_t)li * C_CLS + li];   // == 1.0 by construction, keep general
    float part = 0.0f;
    #pragma unroll
    for (int k = 0; k < PER_T; ++k) {
        const int j2 = t + k * BLK;
        if (j2 < C2) {
            const float2 sv = srow[j2];
            const float ex = expf(l[k].x - m);
            const float ey = expf(l[k].y - m);
            part = fmaf(sv.x, ex, part);
            part = fmaf(sv.y, ey, part);
        }
    }
    #pragma unroll
    for (int off = 32; off > 0; off >>= 1)
        part += __shfl_down(part, off);
    if (lane == 0) red_sum[wv] = part;
    __syncthreads();

    if (t == 0) {
        const float denom_full = red_sum[0] + red_sum[1] + red_sum[2] + red_sum[3];
        const float ei  = expf(lv - m);
        const float denom = denom_full - sii * ei + ei;
        row_loss[n] = logf(denom + EPS_F) - (lv - m);
    }
}

// Deterministic mean of N_ROWS f32 losses, accumulated in double.
// float4-vectorized: 32768 floats = 8192 float4 -> 32 iters of 256 threads.
__global__ __launch_bounds__(BLK) void reduce_mean_kernel(
    const float* __restrict__ row_loss, float* __restrict__ out)
{
    const int t    = threadIdx.x;
    const int lane = t & 63;
    const int wv   = t >> 6;
    const float4* rl4 = reinterpret_cast<const float4*>(row_loss);
    constexpr int N4 = N_ROWS / 4;
    double acc = 0.0;
    #pragma unroll 4
    for (int i = t; i < N4; i += BLK) {
        const float4 v = rl4[i];
        acc += (double)v.x + (double)v.y + (double)v.z + (double)v.w;
    }
    #pragma unroll
    for (int off = 32; off > 0; off >>= 1)
        acc += __shfl_down(acc, off);
    __shared__ double red[4];
    if (lane == 0) red[wv] = acc;
    __syncthreads();
    if (t == 0) {
        const double tot = red[0] + red[1] + red[2] + red[3];
        out[0] = (float)(tot / (double)N_ROWS);
    }
}

extern "C" void kernel_launch(void* const* d_in, const int* in_sizes, int n_in,
                              void* d_out, int out_size, void* d_ws, size_t ws_size,
                              hipStream_t stream) {
    const float* logits  = (const float*)d_in[0];   // [N, C]
    const float* targets = (const float*)d_in[1];   // [N, C] one-hot f32
    const float* s       = (const float*)d_in[2];   // [C, C]
    float* out      = (float*)d_out;                // scalar f32
    float* row_loss = (float*)d_ws;                 // needs N_ROWS*4 = 128 KiB scratch

    seesaw_row_kernel<<<N_ROWS, BLK, 0, stream>>>(logits, targets, s, row_loss);
    reduce_mean_kernel<<<1, BLK, 0, stream>>>(row_loss, out);
}

// Round 5
// 330.419 us; speedup vs baseline: 1.0086x; 1.0086x over previous
//
#include <hip/hip_runtime.h>
#include <math.h>

// SeesawLoss, one-hot specialization, wave-per-row:
//   loss[n] = log(denom[n] + eps) - (l[n,i] - m[n]),  i = label of row n
//   denom[n] = sum_j s[i,j]*e[n,j] - s[i,i]*e[n,i] + e[n,i],  e = exp(l - m)
// One wave64 owns one row: no LDS, no __syncthreads, butterfly shfl reduces.
// Waves are independent -> Phase A (loads) of some waves overlaps Phase B
// (expf+dot) of others without barrier coupling. __expf/__logf cut the
// transcendental cost ~10x vs libm expf.
// Traffic floor: logits 161MB + targets 161MB + s gather (6MB unique, L3) ~ 52us.

constexpr int N_ROWS = 32768;
constexpr int C_CLS  = 1230;
constexpr int C2     = C_CLS / 2;   // 615 float2 per row (4920B rows, 8B-aligned)
constexpr int BLK    = 256;
constexpr int WPB    = BLK / 64;    // 4 waves (rows) per block
constexpr int ITERS  = (C2 + 63) / 64;  // 10
constexpr float EPS_F = 1e-6f;

__global__ __launch_bounds__(BLK) void seesaw_row_kernel(
    const float* __restrict__ logits,
    const float* __restrict__ targets,
    const float* __restrict__ s,
    float* __restrict__ row_loss)
{
    const int t    = threadIdx.x;
    const int lane = t & 63;
    const int wv   = t >> 6;
    const int n    = blockIdx.x * WPB + wv;

    const float2* lrow = reinterpret_cast<const float2*>(logits  + (size_t)n * C_CLS);
    const float2* trow = reinterpret_cast<const float2*>(targets + (size_t)n * C_CLS);

    // ---- Phase A: load row into registers, find max + label (branchless) ---
    float2 l[ITERS];
    float lmax = -INFINITY;
    float lval = 0.0f;   // logit at the hot column (sum-reduce picks it)
    int   li   = 0;      // hot column index (sum-reduce; exactly one hot)

    #pragma unroll
    for (int it = 0; it < ITERS; ++it) {
        const int j2 = lane + it * 64;
        if (j2 < C2) {
            l[it] = lrow[j2];
            const float2 tv = trow[j2];
            lmax = fmaxf(lmax, fmaxf(l[it].x, l[it].y));
            if (tv.x > 0.5f) { li = 2 * j2;     lval = l[it].x; }
            if (tv.y > 0.5f) { li = 2 * j2 + 1; lval = l[it].y; }
        }
    }
    // wave64 butterfly: max(lmax), sum(li), sum(lval) — all lanes get results
    #pragma unroll
    for (int off = 32; off > 0; off >>= 1) {
        lmax  = fmaxf(lmax, __shfl_xor(lmax, off));
        li   += __shfl_xor(li, off);
        lval += __shfl_xor(lval, off);
    }
    const int   li_u = __builtin_amdgcn_readfirstlane(li);  // wave-uniform -> SGPR base
    const float m    = lmax;

    // ---- Phase B: dot( s[li,:], exp(l - m) ) -------------------------------
    const float2* srow = reinterpret_cast<const float2*>(s + (size_t)li_u * C_CLS);
    const float sii = s[(size_t)li_u * C_CLS + li_u];   // ==1.0 by construction

    float part = 0.0f;
    #pragma unroll
    for (int it = 0; it < ITERS; ++it) {
        const int j2 = lane + it * 64;
        if (j2 < C2) {
            const float2 sv = srow[j2];
            part = fmaf(sv.x, __expf(l[it].x - m), part);
            part = fmaf(sv.y, __expf(l[it].y - m), part);
        }
    }
    #pragma unroll
    for (int off = 32; off > 0; off >>= 1)
        part += __shfl_xor(part, off);

    if (lane == 0) {
        const float ei    = __expf(lval - m);
        const float denom = part - sii * ei + ei;
        row_loss[n] = __logf(denom + EPS_F) - (lval - m);
    }
}

// Deterministic mean of N_ROWS f32 losses, accumulated in double.
__global__ __launch_bounds__(BLK) void reduce_mean_kernel(
    const float* __restrict__ row_loss, float* __restrict__ out)
{
    const int t    = threadIdx.x;
    const int lane = t & 63;
    const int wv   = t >> 6;
    const float4* rl4 = reinterpret_cast<const float4*>(row_loss);
    constexpr int N4 = N_ROWS / 4;
    double acc = 0.0;
    #pragma unroll 4
    for (int i = t; i < N4; i += BLK) {
        const float4 v = rl4[i];
        acc += (double)v.x + (double)v.y + (double)v.z + (double)v.w;
    }
    #pragma unroll
    for (int off = 32; off > 0; off >>= 1)
        acc += __shfl_down(acc, off);
    __shared__ double red[4];
    if (lane == 0) red[wv] = acc;
    __syncthreads();
    if (t == 0) {
        const double tot = red[0] + red[1] + red[2] + red[3];
        out[0] = (float)(tot / (double)N_ROWS);
    }
}

extern "C" void kernel_launch(void* const* d_in, const int* in_sizes, int n_in,
                              void* d_out, int out_size, void* d_ws, size_t ws_size,
                              hipStream_t stream) {
    const float* logits  = (const float*)d_in[0];   // [N, C]
    const float* targets = (const float*)d_in[1];   // [N, C] one-hot f32
    const float* s       = (const float*)d_in[2];   // [C, C]
    float* out      = (float*)d_out;                // scalar f32
    float* row_loss = (float*)d_ws;                 // N_ROWS*4 = 128 KiB scratch

    seesaw_row_kernel<<<N_ROWS / WPB, BLK, 0, stream>>>(logits, targets, s, row_loss);
    reduce_mean_kernel<<<1, BLK, 0, stream>>>(row_loss, out);
}

// Round 9
// 323.533 us; speedup vs baseline: 1.0300x; 1.0213x over previous
//
#include <hip/hip_runtime.h>
#include <math.h>

// SeesawLoss, one-hot specialization, two-pass:
//   Pass 1 (label_kernel): flat float4 scan of targets -> labels[n] (argmax of one-hot).
//     Pure streaming, no dependency walls: 161MB at ~memcpy speed.
//   Pass 2 (seesaw_row_kernel): wave-per-row. Label known at wave start, so the
//     logits stream and the s[label,:] gather are issued as ONE batch of ~21
//     independent loads (~10KB in flight per wave) -> latency-tolerant.
//   loss[n] = log(denom+eps) - (l[n,li] - m),  denom = sum_j s[li,j]e_j - s[li,li]e_li + e_li
// Round-5 lesson: VGPR=28 starved the load pipeline (1KB in flight, 24% HBM,
// 13% VALU -> latency-bound). This version spends ~52 VGPRs to buy flight depth.

constexpr int N_ROWS = 32768;
constexpr int C_CLS  = 1230;
constexpr int C2     = C_CLS / 2;        // 615 float2 per row
constexpr int BLK    = 256;
constexpr int WPB    = BLK / 64;         // 4 rows per block
constexpr int ITERS  = (C2 + 63) / 64;   // 10
constexpr unsigned TOT  = (unsigned)N_ROWS * (unsigned)C_CLS;  // 40,304,640
constexpr unsigned TOT4 = TOT / 4;                             // 10,076,160
constexpr float EPS_F = 1e-6f;

// ---- Pass 1: extract labels from one-hot targets (flat float4 stream) ------
__global__ __launch_bounds__(BLK) void label_kernel(
    const float* __restrict__ targets, int* __restrict__ labels)
{
    const float4* t4 = reinterpret_cast<const float4*>(targets);
    const unsigned stride = gridDim.x * BLK;
    for (unsigned i = blockIdx.x * BLK + threadIdx.x; i < TOT4; i += stride) {
        const float4 v = t4[i];
        if (v.x > 0.5f || v.y > 0.5f || v.z > 0.5f || v.w > 0.5f) {  // rare (1/308)
            const unsigned g = i * 4u;
            #pragma unroll
            for (int e = 0; e < 4; ++e) {
                const float val = (e == 0) ? v.x : (e == 1) ? v.y : (e == 2) ? v.z : v.w;
                if (val > 0.5f) {
                    const unsigned gg = g + (unsigned)e;
                    const unsigned n  = gg / (unsigned)C_CLS;   // magic-mul, compile-time const
                    const unsigned c  = gg - n * (unsigned)C_CLS;
                    labels[n] = (int)c;
                }
            }
        }
    }
}

// ---- Pass 2: per-row loss, wave-per-row, deep load batch -------------------
__global__ __launch_bounds__(BLK) void seesaw_row_kernel(
    const float* __restrict__ logits,
    const float* __restrict__ s,
    const int*   __restrict__ labels,
    float* __restrict__ row_loss)
{
    const int t    = threadIdx.x;
    const int lane = t & 63;
    const int wv   = t >> 6;
    const int n    = blockIdx.x * WPB + wv;

    // 1) label first (longest chain: needed for the s-row base)
    const int li = __builtin_amdgcn_readfirstlane(labels[n]);

    // 2) logits row: 10 independent float2 loads (don't depend on li)
    const float2* lrow = reinterpret_cast<const float2*>(logits + (size_t)n * C_CLS);
    float2 l[ITERS];
    #pragma unroll
    for (int it = 0; it < ITERS; ++it) {
        const int j2  = lane + it * 64;
        const int j2c = (j2 < C2) ? j2 : 0;     // clamp; invalid lanes masked later
        l[it] = lrow[j2c];
    }

    // 3) s row gather + scalars: 10 more independent loads (L2/L3-resident)
    const float2* srow = reinterpret_cast<const float2*>(s + (size_t)li * C_CLS);
    float2 sv[ITERS];
    #pragma unroll
    for (int it = 0; it < ITERS; ++it) {
        const int j2  = lane + it * 64;
        const int j2c = (j2 < C2) ? j2 : 0;
        sv[it] = srow[j2c];
    }
    const float lval = logits[(size_t)n * C_CLS + li];   // broadcast load
    const float sii  = s[(size_t)li * C_CLS + li];       // == 1.0 by construction

    // 4) row max (mask invalid lanes), wave64 butterfly
    float lmax = -INFINITY;
    #pragma unroll
    for (int it = 0; it < ITERS; ++it) {
        const int j2 = lane + it * 64;
        if (j2 < C2) lmax = fmaxf(lmax, fmaxf(l[it].x, l[it].y));
    }
    #pragma unroll
    for (int off = 32; off > 0; off >>= 1)
        lmax = fmaxf(lmax, __shfl_xor(lmax, off));
    const float m = lmax;

    // 5) dot( s[li,:], exp(l - m) ) from registers
    float part = 0.0f;
    #pragma unroll
    for (int it = 0; it < ITERS; ++it) {
        const int j2 = lane + it * 64;
        if (j2 < C2) {
            part = fmaf(sv[it].x, __expf(l[it].x - m), part);
            part = fmaf(sv[it].y, __expf(l[it].y - m), part);
        }
    }
    #pragma unroll
    for (int off = 32; off > 0; off >>= 1)
        part += __shfl_xor(part, off);

    if (lane == 0) {
        const float ei    = __expf(lval - m);
        const float denom = part - sii * ei + ei;
        row_loss[n] = __logf(denom + EPS_F) - (lval - m);
    }
}

// ---- Deterministic mean (double accum), one 1024-thread block --------------
__global__ __launch_bounds__(1024) void reduce_mean_kernel(
    const float* __restrict__ row_loss, float* __restrict__ out)
{
    const int t    = threadIdx.x;
    const int lane = t & 63;
    const int wv   = t >> 6;                    // 16 waves
    const float4* rl4 = reinterpret_cast<const float4*>(row_loss);
    constexpr int N4 = N_ROWS / 4;              // 8192
    double acc = 0.0;
    #pragma unroll 8
    for (int i = t; i < N4; i += 1024) {
        const float4 v = rl4[i];
        acc += (double)v.x + (double)v.y + (double)v.z + (double)v.w;
    }
    #pragma unroll
    for (int off = 32; off > 0; off >>= 1)
        acc += __shfl_down(acc, off);
    __shared__ double red[16];
    if (lane == 0) red[wv] = acc;
    __syncthreads();
    if (t == 0) {
        double tot = 0.0;
        #pragma unroll
        for (int w = 0; w < 16; ++w) tot += red[w];
        out[0] = (float)(tot / (double)N_ROWS);
    }
}

extern "C" void kernel_launch(void* const* d_in, const int* in_sizes, int n_in,
                              void* d_out, int out_size, void* d_ws, size_t ws_size,
                              hipStream_t stream) {
    const float* logits  = (const float*)d_in[0];   // [N, C]
    const float* targets = (const float*)d_in[1];   // [N, C] one-hot f32
    const float* s       = (const float*)d_in[2];   // [C, C]
    float* out = (float*)d_out;                     // scalar f32

    int*   labels   = (int*)d_ws;                           // 128 KiB
    float* row_loss = (float*)((char*)d_ws + N_ROWS * 4);   // 128 KiB

    label_kernel<<<2048, BLK, 0, stream>>>(targets, labels);
    seesaw_row_kernel<<<N_ROWS / WPB, BLK, 0, stream>>>(logits, s, labels, row_loss);
    reduce_mean_kernel<<<1, 1024, 0, stream>>>(row_loss, out);
}